// Round 1
// baseline (533.435 us; speedup 1.0000x reference)
//
#include <hip/hip_runtime.h>

// VarianceLoss: softmax over C=4 channels, per-(batch,segment) variance of
// per-channel probabilities, masked mean.  B=8, C=4, H=W=1024, NSEG=65.
//
// Stage 1 (vl_accum): grid (128 blocks/batch, 8 batches) x 256 threads.
//   Each thread processes 4-pixel quads via float4/int4 loads (coalesced),
//   computes the 4-way softmax, and accumulates {sum_c, sumsq_c, cnt} (9 f32)
//   into LDS accumulators privatized 8x per block (per 32-lane group, odd
//   stride to spread banks).  Block epilogue reduces the 8 replicas and
//   unsafeAtomicAdd's 585 floats into the global workspace.
// Stage 2 (vl_finalize): one block reproduces the reference masking math and
//   writes the scalar loss.

constexpr int   NSEG_    = 65;
constexpr int   B_       = 8;
constexpr int   ACCW     = NSEG_ * 9;   // 585 floats per (batch) accumulator
constexpr int   REP      = 8;           // LDS replicas per block
constexpr int   RSTRIDE  = 593;         // odd stride: spreads banks, >= ACCW
constexpr float EPS_     = 1e-8f;

__global__ __launch_bounds__(256) void vl_accum(const float* __restrict__ logit,
                                                const int*   __restrict__ inst,
                                                float* __restrict__ acc,
                                                int N, int ppb)
{
    __shared__ float lacc[REP * RSTRIDE];
    const int tid = threadIdx.x;
    for (int i = tid; i < REP * RSTRIDE; i += 256) lacc[i] = 0.0f;
    __syncthreads();

    const int b = blockIdx.y;
    const float* __restrict__ l0 = logit + (size_t)b * 4 * N;
    const int*   __restrict__ ib = inst  + (size_t)b * N;
    float* my = lacc + ((tid >> 5) * RSTRIDE);

    const int start = blockIdx.x * ppb;
    const int end   = min(start + ppb, N);

    for (int n = start + (tid << 2); n + 3 < end; n += 256 * 4) {
        float4 x0 = *(const float4*)(l0 + n);
        float4 x1 = *(const float4*)(l0 + (size_t)N     + n);
        float4 x2 = *(const float4*)(l0 + (size_t)2 * N + n);
        float4 x3 = *(const float4*)(l0 + (size_t)3 * N + n);
        int4   sg = *(const int4*)(ib + n);

        float a0[4] = {x0.x, x0.y, x0.z, x0.w};
        float a1[4] = {x1.x, x1.y, x1.z, x1.w};
        float a2[4] = {x2.x, x2.y, x2.z, x2.w};
        float a3[4] = {x3.x, x3.y, x3.z, x3.w};
        int   ss[4] = {sg.x, sg.y, sg.z, sg.w};

#pragma unroll
        for (int j = 0; j < 4; ++j) {
            float va = a0[j], vb = a1[j], vc = a2[j], vd = a3[j];
            float m  = fmaxf(fmaxf(va, vb), fmaxf(vc, vd));
            float e0 = __expf(va - m);
            float e1 = __expf(vb - m);
            float e2 = __expf(vc - m);
            float e3 = __expf(vd - m);
            float r  = 1.0f / (e0 + e1 + e2 + e3);
            float p0 = e0 * r, p1 = e1 * r, p2 = e2 * r, p3 = e3 * r;
            float* q = my + ss[j] * 9;
            atomicAdd(q + 0, p0);
            atomicAdd(q + 1, p1);
            atomicAdd(q + 2, p2);
            atomicAdd(q + 3, p3);
            atomicAdd(q + 4, p0 * p0);
            atomicAdd(q + 5, p1 * p1);
            atomicAdd(q + 6, p2 * p2);
            atomicAdd(q + 7, p3 * p3);
            atomicAdd(q + 8, 1.0f);
        }
    }

    // scalar tail (generality; no-op for the given shape)
    int tailStart = start + ((end - start) & ~3);
    for (int n = tailStart + tid; n < end; n += 256) {
        float va = l0[n], vb = l0[(size_t)N + n], vc = l0[(size_t)2 * N + n], vd = l0[(size_t)3 * N + n];
        float m  = fmaxf(fmaxf(va, vb), fmaxf(vc, vd));
        float e0 = __expf(va - m), e1 = __expf(vb - m), e2 = __expf(vc - m), e3 = __expf(vd - m);
        float r  = 1.0f / (e0 + e1 + e2 + e3);
        float p0 = e0 * r, p1 = e1 * r, p2 = e2 * r, p3 = e3 * r;
        float* q = my + ib[n] * 9;
        atomicAdd(q + 0, p0); atomicAdd(q + 1, p1); atomicAdd(q + 2, p2); atomicAdd(q + 3, p3);
        atomicAdd(q + 4, p0 * p0); atomicAdd(q + 5, p1 * p1); atomicAdd(q + 6, p2 * p2); atomicAdd(q + 7, p3 * p3);
        atomicAdd(q + 8, 1.0f);
    }

    __syncthreads();

    float* gacc = acc + (size_t)b * ACCW;
    for (int i = tid; i < ACCW; i += 256) {
        float v = 0.0f;
#pragma unroll
        for (int rpl = 0; rpl < REP; ++rpl) v += lacc[rpl * RSTRIDE + i];
        unsafeAtomicAdd(gacc + i, v);
    }
}

__global__ __launch_bounds__(256) void vl_finalize(const float* __restrict__ acc,
                                                   float* __restrict__ out)
{
    __shared__ float sum_var[B_];
    __shared__ float num_ids[B_];
    if (threadIdx.x < B_) { sum_var[threadIdx.x] = 0.0f; num_ids[threadIdx.x] = 0.0f; }
    __syncthreads();

    for (int i = threadIdx.x; i < B_ * NSEG_; i += blockDim.x) {
        int b = i / NSEG_;
        int s = i - b * NSEG_;
        if (s == 0) continue;                    // nonzero_id mask
        const float* a = acc + (size_t)i * 9;
        float cnt = a[8];
        if (cnt > 1.0f) {
            float inv_n  = 1.0f / cnt;           // n_safe = cnt (cnt > 0)
            float denom  = cnt - 1.0f;           // cnt > 1
            float sv = 0.0f;
#pragma unroll
            for (int c = 0; c < 4; ++c) {
                float sm = a[c], sq = a[4 + c];
                sv += (sq - sm * sm * inv_n) / denom;
            }
            atomicAdd(&sum_var[b], sv);
        }
        if (cnt > 0.0f) atomicAdd(&num_ids[b], 1.0f);
    }
    __syncthreads();

    if (threadIdx.x == 0) {
        float loss = 0.0f;
#pragma unroll
        for (int b = 0; b < B_; ++b) loss += sum_var[b] / (num_ids[b] + EPS_);
        out[0] = loss / (float)B_;
    }
}

extern "C" void kernel_launch(void* const* d_in, const int* in_sizes, int n_in,
                              void* d_out, int out_size, void* d_ws, size_t ws_size,
                              hipStream_t stream) {
    const float* logit = (const float*)d_in[0];
    const int*   inst  = (const int*)d_in[1];
    float* out = (float*)d_out;
    float* acc = (float*)d_ws;                   // B_*ACCW floats = 18720 B

    const int totalPix = in_sizes[1];            // B*H*W
    const int N = totalPix / B_;                 // H*W per batch

    hipMemsetAsync(acc, 0, (size_t)B_ * ACCW * sizeof(float), stream);

    const int gridx = 128;
    int ppb = (N + gridx - 1) / gridx;
    ppb = (ppb + 3) & ~3;                        // quad-aligned

    dim3 grid(gridx, B_);
    vl_accum<<<grid, 256, 0, stream>>>(logit, inst, acc, N, ppb);
    vl_finalize<<<1, 256, 0, stream>>>(acc, out);
}

// Round 3
// 505.682 us; speedup vs baseline: 1.0549x; 1.0549x over previous
//
#include <hip/hip_runtime.h>

// VarianceLoss, owner-lane formulation.  B=8, C=4, H=W=1024, NSEG=65.
//
// Reference masks out segment 0 entirely (nonzero_id), so only segments
// 1..64 matter -- exactly 64, one per lane.  Each lane owns segment lane+1
// and keeps 5 register accumulators {s0,s1,s2,sq_tot,cnt}; sum_p3 is
// recovered at finalize as cnt - s0 - s1 - s2 (p's sum to 1).  Per 64-pixel
// wave round, each pixel's (seg, p0,p1,p2, sq) is broadcast via v_readlane
// and every lane conditionally accumulates (one cmp+cndmask mask, 4 fmac,
// 1 add).  No LDS, no atomics in the hot loop (R1: ds_add_f32 ~200 cyc/
// wave-instr = 385 us).  Epilogue: 5 global unsafeAtomicAdd per lane,
// distinct addresses within a wave.

constexpr int   B_    = 8;
constexpr int   SEGS  = 64;     // segments 1..64 (segment 0 is masked out)
constexpr int   VALS  = 5;      // s0,s1,s2,sq_tot,cnt
constexpr float EPS_  = 1e-8f;

__device__ __forceinline__ float bcastf(float v, int j) {
    return __uint_as_float(__builtin_amdgcn_readlane(__float_as_uint(v), j));
}

__global__ __launch_bounds__(256) void vl_accum(const float* __restrict__ logit,
                                                const int*   __restrict__ inst,
                                                float* __restrict__ acc,
                                                int N, int ppb)
{
    const int b = blockIdx.y;
    const float* __restrict__ l0 = logit + (size_t)b * 4 * N;
    const int*   __restrict__ ib = inst  + (size_t)b * N;
    const int myseg = (threadIdx.x & 63) + 1;

    float a0 = 0.f, a1 = 0.f, a2 = 0.f, asq = 0.f, acnt = 0.f;

    const int start  = blockIdx.x * ppb;
    const int rounds = ppb >> 10;              // 256 threads x 4 px per round

    for (int k = 0; k < rounds; ++k) {
        const int n  = start + (k << 10) + ((int)threadIdx.x << 2);
        const bool ok = (n + 4 <= N);
        const int nc = ok ? n : 0;

        float4 x0 = *(const float4*)(l0 + nc);
        float4 x1 = *(const float4*)(l0 + (size_t)N     + nc);
        float4 x2 = *(const float4*)(l0 + (size_t)2 * N + nc);
        float4 x3 = *(const float4*)(l0 + (size_t)3 * N + nc);
        int4   sg = *(const int4*)(ib + nc);
        if (!ok) sg = make_int4(0, 0, 0, 0);   // seg 0 has no owner -> dropped

        const float c0[4] = {x0.x, x0.y, x0.z, x0.w};
        const float c1[4] = {x1.x, x1.y, x1.z, x1.w};
        const float c2[4] = {x2.x, x2.y, x2.z, x2.w};
        const float c3[4] = {x3.x, x3.y, x3.z, x3.w};
        const int  sgs[4] = {sg.x, sg.y, sg.z, sg.w};

        float p0[4], p1[4], p2[4], qq[4];
#pragma unroll
        for (int r = 0; r < 4; ++r) {
            float va = c0[r], vb = c1[r], vc = c2[r], vd = c3[r];
            float m  = fmaxf(fmaxf(va, vb), fmaxf(vc, vd));
            float e0 = __expf(va - m);
            float e1 = __expf(vb - m);
            float e2 = __expf(vc - m);
            float e3 = __expf(vd - m);
            float rr = 1.0f / (e0 + e1 + e2 + e3);
            float q0 = e0 * rr, q1 = e1 * rr, q2 = e2 * rr, q3 = e3 * rr;
            p0[r] = q0; p1[r] = q1; p2[r] = q2;
            qq[r] = q0*q0 + q1*q1 + q2*q2 + q3*q3;
        }

#pragma unroll
        for (int r = 0; r < 4; ++r) {
#pragma unroll 8
            for (int j = 0; j < 64; ++j) {
                const int   ss  = __builtin_amdgcn_readlane(sgs[r], j);
                const float sp0 = bcastf(p0[r], j);
                const float sp1 = bcastf(p1[r], j);
                const float sp2 = bcastf(p2[r], j);
                const float ssq = bcastf(qq[r], j);
                const float m   = (ss == myseg) ? 1.0f : 0.0f;
                a0   = fmaf(sp0, m, a0);
                a1   = fmaf(sp1, m, a1);
                a2   = fmaf(sp2, m, a2);
                asq  = fmaf(ssq, m, asq);
                acnt += m;
            }
        }
    }

    float* dst = acc + ((size_t)b * SEGS + (threadIdx.x & 63)) * VALS;
    unsafeAtomicAdd(dst + 0, a0);
    unsafeAtomicAdd(dst + 1, a1);
    unsafeAtomicAdd(dst + 2, a2);
    unsafeAtomicAdd(dst + 3, asq);
    unsafeAtomicAdd(dst + 4, acnt);
}

__global__ __launch_bounds__(256) void vl_finalize(const float* __restrict__ acc,
                                                   float* __restrict__ out)
{
    __shared__ float sum_var[B_];
    __shared__ float num_ids[B_];
    if (threadIdx.x < B_) { sum_var[threadIdx.x] = 0.0f; num_ids[threadIdx.x] = 0.0f; }
    __syncthreads();

    for (int i = threadIdx.x; i < B_ * SEGS; i += 256) {
        const float* a = acc + (size_t)i * VALS;
        const int b = i >> 6;
        const float cnt = a[4];
        if (cnt > 1.0f) {
            const float inv_n = 1.0f / cnt;      // n_safe = cnt (cnt > 0)
            const float denom = cnt - 1.0f;      // cnt > 1
            const float s0 = a[0], s1 = a[1], s2 = a[2];
            const float s3 = cnt - s0 - s1 - s2; // p's sum to 1 per pixel
            const float ssum2 = s0*s0 + s1*s1 + s2*s2 + s3*s3;
            const float sv = (a[3] - ssum2 * inv_n) / denom;
            atomicAdd(&sum_var[b], sv);
        }
        if (cnt > 0.0f) atomicAdd(&num_ids[b], 1.0f);
    }
    __syncthreads();

    if (threadIdx.x == 0) {
        float loss = 0.0f;
#pragma unroll
        for (int b = 0; b < B_; ++b) loss += sum_var[b] / (num_ids[b] + EPS_);
        out[0] = loss / (float)B_;
    }
}

extern "C" void kernel_launch(void* const* d_in, const int* in_sizes, int n_in,
                              void* d_out, int out_size, void* d_ws, size_t ws_size,
                              hipStream_t stream) {
    const float* logit = (const float*)d_in[0];
    const int*   inst  = (const int*)d_in[1];
    float* out = (float*)d_out;
    float* acc = (float*)d_ws;                     // B_*SEGS*VALS f32 = 10240 B

    const int totalPix = in_sizes[1];              // B*H*W
    const int N = totalPix / B_;                   // H*W per batch

    hipMemsetAsync(acc, 0, (size_t)B_ * SEGS * VALS * sizeof(float), stream);

    const int gridx = 256;
    int ppb = (N + gridx - 1) / gridx;
    ppb = (ppb + 1023) & ~1023;                    // 1024-pixel rounds

    dim3 grid(gridx, B_);
    vl_accum<<<grid, 256, 0, stream>>>(logit, inst, acc, N, ppb);
    vl_finalize<<<1, 256, 0, stream>>>(acc, out);
}

// Round 4
// 220.899 us; speedup vs baseline: 2.4148x; 2.2892x over previous
//
#include <hip/hip_runtime.h>

// VarianceLoss via one-hot MFMA segment reduction.  B=8, C=4, H=W=1024, NSEG=65.
//
// C[64 segs][cols] += Onehot[seg][px] * Payload[px][cols], K = pixels.
//  - A (one-hot, exact 0/1 in bf16) built in registers from staged seg ids
//    with packed u16 ops.  B = staged payload, bf16 hi+lo split: cols 0..4 =
//    {p0,p1,p2,qq,1(cnt)} hi, cols 8..12 = lo parts (col12 zero).  hi+lo
//    merged in the epilogue => full ~f32 precision from bf16 MFMAs.
//  - A and B fragments are addressed through the SAME assumed (lane>>4,j)->k
//    map, so a wrong assumption cancels (A/B k-layouts are symmetric).
//  - Each wave stages into its own LDS region: no barriers in the main loop.
//    p3 is recovered at finalize as cnt - p0 - p1 - p2.

typedef unsigned int  uint32_t_;
typedef unsigned short u16x2 __attribute__((ext_vector_type(2)));
typedef unsigned int   u32x4 __attribute__((ext_vector_type(4)));
typedef short          s16x8 __attribute__((ext_vector_type(8)));   // 8 x bf16
typedef float          f32x4 __attribute__((ext_vector_type(4)));

constexpr int   B_    = 8;
constexpr int   SEGS  = 64;      // segments 1..64 (segment 0 masked out by ref)
constexpr int   VALS  = 5;       // p0,p1,p2,qq,cnt
constexpr float EPS_  = 1e-8f;

constexpr int PLANE   = 528;               // bytes per plane (512 + bank skew)
constexpr int NSLOT   = 11;                // 4 hi, 4 lo, ONES, ZERO, seg
constexpr int WLDS    = NSLOT * PLANE;     // 5808 B per wave
constexpr int LDS_SZ  = (4 * WLDS > 16384) ? 4 * WLDS : 16384;

__device__ __forceinline__ unsigned asu(float f)  { return __float_as_uint(f); }
__device__ __forceinline__ float    asf(unsigned u){ return __uint_as_float(u); }

__global__ __launch_bounds__(256) void vl_accum(const float* __restrict__ logit,
                                                const int*   __restrict__ inst,
                                                float* __restrict__ acc,
                                                int N, int ppb)
{
    __shared__ __align__(16) unsigned char lds[LDS_SZ];

    const int tid  = threadIdx.x;
    const int wid  = tid >> 6;
    const int lane = tid & 63;
    const int col  = lane & 15;
    const int quad = lane >> 4;
    const int wbase = wid * WLDS;

    // init ONES (slot 8) and ZERO (slot 9) planes, 512B each used
    *(uint2*)(lds + wbase + 8 * PLANE + lane * 8) = make_uint2(0x3F803F80u, 0x3F803F80u);
    *(uint2*)(lds + wbase + 9 * PLANE + lane * 8) = make_uint2(0u, 0u);

    // B-read plane per column
    int pl;
    if      (col < 4)              pl = col;        // hi payload
    else if (col >= 8 && col < 12) pl = col - 4;    // lo payload
    else if (col == 4)             pl = 8;          // cnt hi = 1.0
    else                           pl = 9;          // zero
    const int bRd   = wbase + pl * PLANE + quad * 16;   // + kt*64
    const int segRd = wbase + 10 * PLANE + quad * 16;   // + kt*64
    const int segWr = wbase + 10 * PLANE + lane * 8;

    u16x2 rowdup[4];
#pragma unroll
    for (int t = 0; t < 4; ++t) {
        unsigned short rw = (unsigned short)(t * 16 + col);
        rowdup[t] = (u16x2){rw, rw};
    }
    const u16x2 one2  = (u16x2){1, 1};
    const u16x2 bf1p  = (u16x2){0x3F80, 0x3F80};

    const int b = blockIdx.y;
    const float* __restrict__ l0 = logit + (size_t)b * 4 * N;
    const int*   __restrict__ ib = inst  + (size_t)b * N;

    f32x4 acc0 = {0.f,0.f,0.f,0.f}, acc1 = {0.f,0.f,0.f,0.f};
    f32x4 acc2 = {0.f,0.f,0.f,0.f}, acc3 = {0.f,0.f,0.f,0.f};

    const int blockStart = blockIdx.x * ppb;
    const int rounds = ppb >> 10;

    for (int r = 0; r < rounds; ++r) {
        const int q  = blockStart + (r << 10) + (wid << 8) + (lane << 2);
        const bool ok = (q + 4 <= N);
        const int qc = ok ? q : 0;

        float4 x0 = *(const float4*)(l0 + qc);
        float4 x1 = *(const float4*)(l0 + (size_t)N     + qc);
        float4 x2 = *(const float4*)(l0 + (size_t)2 * N + qc);
        float4 x3 = *(const float4*)(l0 + (size_t)3 * N + qc);
        int4   sg = *(const int4*)(ib + qc);
        if (!ok) sg = make_int4(0, 0, 0, 0);

        const float c0[4] = {x0.x, x0.y, x0.z, x0.w};
        const float c1[4] = {x1.x, x1.y, x1.z, x1.w};
        const float c2[4] = {x2.x, x2.y, x2.z, x2.w};
        const float c3[4] = {x3.x, x3.y, x3.z, x3.w};

        float P0[4], P1[4], P2[4], QQ[4];
#pragma unroll
        for (int i = 0; i < 4; ++i) {
            float va = c0[i], vb = c1[i], vc = c2[i], vd = c3[i];
            float m  = fmaxf(fmaxf(va, vb), fmaxf(vc, vd));
            float e0 = __expf(va - m);
            float e1 = __expf(vb - m);
            float e2 = __expf(vc - m);
            float e3 = __expf(vd - m);
            float rr = 1.0f / (e0 + e1 + e2 + e3);
            float q0 = e0 * rr, q1 = e1 * rr, q2 = e2 * rr, q3 = e3 * rr;
            P0[i] = q0; P1[i] = q1; P2[i] = q2;
            QQ[i] = q0*q0 + q1*q1 + q2*q2 + q3*q3;
        }

        // stage one plane: hi (truncated bf16) to slot p, lo residual to p+4
#define STAGE_PLANE(P, ARR)                                                     \
        {                                                                       \
            unsigned a0 = asu(ARR[0]), a1 = asu(ARR[1]);                        \
            unsigned a2 = asu(ARR[2]), a3 = asu(ARR[3]);                        \
            unsigned h1m = a1 & 0xFFFF0000u, h3m = a3 & 0xFFFF0000u;            \
            unsigned hi01 = (a0 >> 16) | h1m;                                   \
            unsigned hi23 = (a2 >> 16) | h3m;                                   \
            float l0f = ARR[0] - asf(a0 & 0xFFFF0000u);                         \
            float l1f = ARR[1] - asf(h1m);                                      \
            float l2f = ARR[2] - asf(a2 & 0xFFFF0000u);                         \
            float l3f = ARR[3] - asf(h3m);                                      \
            unsigned lo01 = (asu(l0f) >> 16) | (asu(l1f) & 0xFFFF0000u);        \
            unsigned lo23 = (asu(l2f) >> 16) | (asu(l3f) & 0xFFFF0000u);        \
            *(uint2*)(lds + wbase + (P) * PLANE + lane * 8)     = make_uint2(hi01, hi23); \
            *(uint2*)(lds + wbase + ((P)+4) * PLANE + lane * 8) = make_uint2(lo01, lo23); \
        }
        STAGE_PLANE(0, P0)
        STAGE_PLANE(1, P1)
        STAGE_PLANE(2, P2)
        STAGE_PLANE(3, QQ)
#undef STAGE_PLANE

        // seg-1 as u16 (seg 0 / invalid -> 0xFFFF, matches no row)
        {
            unsigned r0 = (unsigned)(sg.x - 1) & 0xFFFFu;
            unsigned r1 = (unsigned)(sg.y - 1) & 0xFFFFu;
            unsigned r2 = (unsigned)(sg.z - 1) & 0xFFFFu;
            unsigned r3 = (unsigned)(sg.w - 1) & 0xFFFFu;
            *(uint2*)(lds + segWr) = make_uint2(r0 | (r1 << 16), r2 | (r3 << 16));
        }
        // own-wave RAW through LDS: compiler inserts lgkmcnt waits.

#pragma unroll
        for (int kt = 0; kt < 8; ++kt) {
            s16x8 bfrag = *(const s16x8*)(lds + bRd   + kt * 64);
            u32x4 sv    = *(const u32x4*)(lds + segRd + kt * 64);

#define DO_TILE(T, ACC)                                                         \
            {                                                                   \
                u32x4 fr;                                                       \
                _Pragma("unroll")                                               \
                for (int i = 0; i < 4; ++i) {                                   \
                    u16x2 sp  = __builtin_bit_cast(u16x2, sv[i]);               \
                    u16x2 d   = sp - rowdup[T];                                 \
                    u16x2 mn  = __builtin_elementwise_min(d, one2);             \
                    u16x2 inv = one2 - mn;                                      \
                    u16x2 f   = inv * bf1p;                                     \
                    fr[i] = __builtin_bit_cast(unsigned, f);                    \
                }                                                               \
                s16x8 afrag = __builtin_bit_cast(s16x8, fr);                    \
                ACC = __builtin_amdgcn_mfma_f32_16x16x32_bf16(afrag, bfrag, ACC, 0, 0, 0); \
            }
            DO_TILE(0, acc0)
            DO_TILE(1, acc1)
            DO_TILE(2, acc2)
            DO_TILE(3, acc3)
#undef DO_TILE
        }
    }

    // ---- cross-wave reduce + global atomics ----
    __syncthreads();                       // all waves done reading their planes
    float* cl = (float*)lds;               // [w][t][lane][reg] f32
    {
        const int base = ((wid * 4) * 64 + lane) * 4;
        *(f32x4*)(cl + base)            = acc0;
        *(f32x4*)(cl + base + 64 * 4)   = acc1;
        *(f32x4*)(cl + base + 128 * 4)  = acc2;
        *(f32x4*)(cl + base + 192 * 4)  = acc3;
    }
    __syncthreads();

    for (int i = tid; i < SEGS * VALS; i += 256) {
        const int row = i / VALS;          // 0..63  (= seg-1)
        const int cc  = i - row * VALS;    // 0..4
        const int t   = row >> 4;
        const int rr  = row & 15;
        const int g   = rr >> 2;
        const int reg = rr & 3;
        const int lhi = g * 16 + cc;
        const int llo = lhi + 8;
        float v = 0.0f;
#pragma unroll
        for (int w = 0; w < 4; ++w) {
            v += cl[((w * 4 + t) * 64 + lhi) * 4 + reg];
            v += cl[((w * 4 + t) * 64 + llo) * 4 + reg];
        }
        unsafeAtomicAdd(acc + ((size_t)blockIdx.y * SEGS + row) * VALS + cc, v);
    }
}

__global__ __launch_bounds__(256) void vl_finalize(const float* __restrict__ acc,
                                                   float* __restrict__ out)
{
    __shared__ float sum_var[B_];
    __shared__ float num_ids[B_];
    if (threadIdx.x < B_) { sum_var[threadIdx.x] = 0.0f; num_ids[threadIdx.x] = 0.0f; }
    __syncthreads();

    for (int i = threadIdx.x; i < B_ * SEGS; i += 256) {
        const float* a = acc + (size_t)i * VALS;
        const int b = i >> 6;
        const float cnt = a[4];
        if (cnt > 1.0f) {
            const float inv_n = 1.0f / cnt;       // n_safe = cnt (cnt > 0)
            const float denom = cnt - 1.0f;       // cnt > 1
            const float s0 = a[0], s1 = a[1], s2 = a[2];
            const float s3 = cnt - s0 - s1 - s2;  // p's sum to 1 per pixel
            const float ssum2 = s0*s0 + s1*s1 + s2*s2 + s3*s3;
            const float sv = (a[3] - ssum2 * inv_n) / denom;
            atomicAdd(&sum_var[b], sv);
        }
        if (cnt > 0.0f) atomicAdd(&num_ids[b], 1.0f);
    }
    __syncthreads();

    if (threadIdx.x == 0) {
        float loss = 0.0f;
#pragma unroll
        for (int b = 0; b < B_; ++b) loss += sum_var[b] / (num_ids[b] + EPS_);
        out[0] = loss / (float)B_;
    }
}

extern "C" void kernel_launch(void* const* d_in, const int* in_sizes, int n_in,
                              void* d_out, int out_size, void* d_ws, size_t ws_size,
                              hipStream_t stream) {
    const float* logit = (const float*)d_in[0];
    const int*   inst  = (const int*)d_in[1];
    float* out = (float*)d_out;
    float* acc = (float*)d_ws;                      // B_*SEGS*VALS f32 = 10240 B

    const int totalPix = in_sizes[1];               // B*H*W
    const int N = totalPix / B_;                    // H*W per batch

    hipMemsetAsync(acc, 0, (size_t)B_ * SEGS * VALS * sizeof(float), stream);

    const int gridx = 128;
    int ppb = (N + gridx - 1) / gridx;
    ppb = (ppb + 1023) & ~1023;                     // 1024-px block rounds

    dim3 grid(gridx, B_);
    vl_accum<<<grid, 256, 0, stream>>>(logit, inst, acc, N, ppb);
    vl_finalize<<<1, 256, 0, stream>>>(acc, out);
}